// Round 1
// baseline (132.764 us; speedup 1.0000x reference)
//
#include <hip/hip_runtime.h>

#define BN 2048
#define BB 32

// Kernel A: compute disc value d_p = log2(rank0_p + 3) for each element,
// where rank0_p = #{q : pred_q > pred_p} + #{q : pred_q == pred_p && q < p}
// (matches stable argsort of -preds). One block per (row, 256-elem chunk).
__global__ __launch_bounds__(256) void rank_disc_kernel(const float* __restrict__ preds,
                                                        float* __restrict__ disc) {
    __shared__ float sp[BN];
    const int row = blockIdx.y;
    const int chunk = blockIdx.x;
    const float* prow = preds + row * BN;

    // Stage full row of preds into LDS (vectorized, coalesced).
    for (int i = threadIdx.x; i < BN / 4; i += 256) {
        ((float4*)sp)[i] = ((const float4*)prow)[i];
    }
    __syncthreads();

    const int p = chunk * 256 + threadIdx.x;
    const float pp = sp[p];
    int cnt = 0;
    // q is wave-uniform -> LDS broadcast reads, no bank conflicts.
    for (int q = 0; q < BN; q += 4) {
        float4 v = ((const float4*)sp)[q >> 2];
        cnt += (v.x > pp) || (v.x == pp && (q + 0) < p);
        cnt += (v.y > pp) || (v.y == pp && (q + 1) < p);
        cnt += (v.z > pp) || (v.z == pp && (q + 2) < p);
        cnt += (v.w > pp) || (v.w == pp && (q + 3) < p);
    }
    disc[row * BN + p] = log2f((float)(cnt + 3));
}

// Kernel B: sum over ordered pairs |t_p - t_q| * |d_p - d_q|, scaled by 1/(2B).
// Grid: (8 p-chunks, B rows, 2 q-halves). Each block stages its q-half of
// (targets, disc) in LDS and accumulates 256 p-lanes x 1024 q.
__global__ __launch_bounds__(256) void pair_sum_kernel(const float* __restrict__ targets,
                                                       const float* __restrict__ disc,
                                                       float* __restrict__ out) {
    __shared__ float st[BN / 2];
    __shared__ float sd[BN / 2];
    const int row = blockIdx.y;
    const int chunk = blockIdx.x;
    const int qhalf = blockIdx.z;
    const float* trow = targets + row * BN;
    const float* drow = disc + row * BN;
    const int qbase = qhalf * (BN / 2);

    for (int i = threadIdx.x; i < BN / 8; i += 256) {
        ((float4*)st)[i] = ((const float4*)(trow + qbase))[i];
        ((float4*)sd)[i] = ((const float4*)(drow + qbase))[i];
    }
    __syncthreads();

    const int p = chunk * 256 + threadIdx.x;
    const float tp = trow[p];
    const float dp = drow[p];
    float acc = 0.0f;
    for (int q = 0; q < BN / 2; q += 4) {
        float4 tv = ((const float4*)st)[q >> 2];
        float4 dv = ((const float4*)sd)[q >> 2];
        acc += fabsf((tp - tv.x) * (dp - dv.x));
        acc += fabsf((tp - tv.y) * (dp - dv.y));
        acc += fabsf((tp - tv.z) * (dp - dv.z));
        acc += fabsf((tp - tv.w) * (dp - dv.w));
    }

    // Wave (64-lane) shuffle reduction, then cross-wave via LDS.
    for (int off = 32; off > 0; off >>= 1) acc += __shfl_down(acc, off, 64);
    __shared__ float warp_acc[4];
    if ((threadIdx.x & 63) == 0) warp_acc[threadIdx.x >> 6] = acc;
    __syncthreads();
    if (threadIdx.x == 0) {
        float s = warp_acc[0] + warp_acc[1] + warp_acc[2] + warp_acc[3];
        atomicAdd(out, s * (1.0f / (2.0f * BB)));
    }
}

extern "C" void kernel_launch(void* const* d_in, const int* in_sizes, int n_in,
                              void* d_out, int out_size, void* d_ws, size_t ws_size,
                              hipStream_t stream) {
    const float* preds = (const float*)d_in[0];
    const float* targets = (const float*)d_in[1];
    float* out = (float*)d_out;
    float* disc = (float*)d_ws;  // B*N floats = 256 KB

    // d_out is poisoned with 0xAA before every launch; clear it (capturable).
    hipMemsetAsync(d_out, 0, sizeof(float), stream);

    dim3 gridA(BN / 256, BB);           // (8, 32)
    rank_disc_kernel<<<gridA, 256, 0, stream>>>(preds, disc);

    dim3 gridB(BN / 256, BB, 2);        // (8, 32, 2)
    pair_sum_kernel<<<gridB, 256, 0, stream>>>(targets, disc, out);
}

// Round 2
// 108.791 us; speedup vs baseline: 1.2204x; 1.2204x over previous
//
#include <hip/hip_runtime.h>

#define BN 2048
#define BB 32

// Kernel A: disc[p] = log2(rank0_p + 3), rank0_p = #{q: pred_q > pred_p}
//                                               + #{q < p: pred_q == pred_p}
// Block = 256 threads = 32 p's x 8 q-octants. Grid (64 pblocks, 32 rows).
// Octants walk the row interleaved (float4 stride 8) to avoid the 8-way
// LDS bank conflict a contiguous split would cause.
__global__ __launch_bounds__(256) void rank_disc_kernel(const float* __restrict__ preds,
                                                        float* __restrict__ disc) {
    __shared__ float sp[BN];
    const int row = blockIdx.y;
    const float* prow = preds + row * BN;

    for (int i = threadIdx.x; i < BN / 4; i += 256) {
        ((float4*)sp)[i] = ((const float4*)prow)[i];
    }
    __syncthreads();

    const int plocal = threadIdx.x >> 3;   // 0..31
    const int qoct   = threadIdx.x & 7;    // 0..7
    const int p = blockIdx.x * 32 + plocal;
    const float pp = sp[p];

    int cnt = 0;
    // 512 float4s per row; each octant takes every 8th float4 (64 iters).
    for (int f = qoct; f < BN / 4; f += 8) {
        float4 v = ((const float4*)sp)[f];
        const int q = f * 4;
        cnt += (v.x > pp) || (v.x == pp && (q + 0) < p);
        cnt += (v.y > pp) || (v.y == pp && (q + 1) < p);
        cnt += (v.z > pp) || (v.z == pp && (q + 2) < p);
        cnt += (v.w > pp) || (v.w == pp && (q + 3) < p);
    }
    // Combine the 8 octant partials (lanes differ only in low 3 bits).
    cnt += __shfl_xor(cnt, 1, 64);
    cnt += __shfl_xor(cnt, 2, 64);
    cnt += __shfl_xor(cnt, 4, 64);
    if (qoct == 0) {
        disc[row * BN + p] = log2f((float)(cnt + 3));
    }
}

// Kernel B: sum over ordered pairs |t_p - t_q| * |d_p - d_q|, scaled 1/(2B).
// Grid (8 pchunks, 32 rows, 8 qoctants); 256-elem q-tile staged in LDS,
// read wave-uniform (broadcast, conflict-free).
__global__ __launch_bounds__(256) void pair_sum_kernel(const float* __restrict__ targets,
                                                       const float* __restrict__ disc,
                                                       float* __restrict__ out) {
    __shared__ float st[256];
    __shared__ float sd[256];
    const int row = blockIdx.y;
    const float* trow = targets + row * BN;
    const float* drow = disc + row * BN;
    const int qbase = blockIdx.z * 256;

    st[threadIdx.x] = trow[qbase + threadIdx.x];
    sd[threadIdx.x] = drow[qbase + threadIdx.x];
    __syncthreads();

    const int p = blockIdx.x * 256 + threadIdx.x;
    const float tp = trow[p];
    const float dp = drow[p];
    float acc = 0.0f;
    for (int q = 0; q < 256; q += 4) {
        float4 tv = ((const float4*)st)[q >> 2];
        float4 dv = ((const float4*)sd)[q >> 2];
        acc += fabsf((tp - tv.x) * (dp - dv.x));
        acc += fabsf((tp - tv.y) * (dp - dv.y));
        acc += fabsf((tp - tv.z) * (dp - dv.z));
        acc += fabsf((tp - tv.w) * (dp - dv.w));
    }

    for (int off = 32; off > 0; off >>= 1) acc += __shfl_down(acc, off, 64);
    __shared__ float warp_acc[4];
    if ((threadIdx.x & 63) == 0) warp_acc[threadIdx.x >> 6] = acc;
    __syncthreads();
    if (threadIdx.x == 0) {
        float s = warp_acc[0] + warp_acc[1] + warp_acc[2] + warp_acc[3];
        atomicAdd(out, s * (1.0f / (2.0f * BB)));
    }
}

extern "C" void kernel_launch(void* const* d_in, const int* in_sizes, int n_in,
                              void* d_out, int out_size, void* d_ws, size_t ws_size,
                              hipStream_t stream) {
    const float* preds = (const float*)d_in[0];
    const float* targets = (const float*)d_in[1];
    float* out = (float*)d_out;
    float* disc = (float*)d_ws;  // B*N floats = 256 KB

    hipMemsetAsync(d_out, 0, sizeof(float), stream);

    dim3 gridA(BN / 32, BB);            // (64, 32) = 2048 blocks
    rank_disc_kernel<<<gridA, 256, 0, stream>>>(preds, disc);

    dim3 gridB(BN / 256, BB, BN / 256); // (8, 32, 8) = 2048 blocks
    pair_sum_kernel<<<gridB, 256, 0, stream>>>(targets, disc, out);
}

// Round 3
// 96.525 us; speedup vs baseline: 1.3754x; 1.1271x over previous
//
#include <hip/hip_runtime.h>

#define BN 2048
#define BB 32
#define NPAIRBLK (8 * 32 * 8)   // pair_sum grid size (p-chunks x rows x q-octants)

// Kernel A: disc[p] = log2(rank0_p + 3), rank0_p = #{q: pred_q > pred_p}
//                                               + #{q < p: pred_q == pred_p}
// Block = 256 threads = 32 p's x 8 q-octants. Grid (64 pblocks, 32 rows).
// Octants walk the row interleaved (float4 stride 8): the 8 lanes of a group
// cover all 32 banks, groups broadcast -> conflict-free (verified: 0 in R1).
__global__ __launch_bounds__(256) void rank_disc_kernel(const float* __restrict__ preds,
                                                        float* __restrict__ disc) {
    __shared__ float sp[BN];
    const int row = blockIdx.y;
    const float* prow = preds + row * BN;

    for (int i = threadIdx.x; i < BN / 4; i += 256) {
        ((float4*)sp)[i] = ((const float4*)prow)[i];
    }
    __syncthreads();

    const int plocal = threadIdx.x >> 3;   // 0..31
    const int qoct   = threadIdx.x & 7;    // 0..7
    const int p = blockIdx.x * 32 + plocal;
    const float pp = sp[p];

    int cnt = 0;
    for (int f = qoct; f < BN / 4; f += 8) {
        float4 v = ((const float4*)sp)[f];
        const int q = f * 4;
        cnt += (v.x > pp) || (v.x == pp && (q + 0) < p);
        cnt += (v.y > pp) || (v.y == pp && (q + 1) < p);
        cnt += (v.z > pp) || (v.z == pp && (q + 2) < p);
        cnt += (v.w > pp) || (v.w == pp && (q + 3) < p);
    }
    cnt += __shfl_xor(cnt, 1, 64);
    cnt += __shfl_xor(cnt, 2, 64);
    cnt += __shfl_xor(cnt, 4, 64);
    if (qoct == 0) {
        disc[row * BN + p] = log2f((float)(cnt + 3));
    }
}

// Kernel B: per-block partial of sum over pairs |t_p - t_q| * |d_p - d_q|.
// Grid (8 pchunks, 32 rows, 8 qoctants). NO atomics: one plain store per
// block into partials[] (2048 same-address atomics cost ~25-30 us in R2).
__global__ __launch_bounds__(256) void pair_sum_kernel(const float* __restrict__ targets,
                                                       const float* __restrict__ disc,
                                                       float* __restrict__ partials) {
    __shared__ float st[256];
    __shared__ float sd[256];
    const int row = blockIdx.y;
    const float* trow = targets + row * BN;
    const float* drow = disc + row * BN;
    const int qbase = blockIdx.z * 256;

    st[threadIdx.x] = trow[qbase + threadIdx.x];
    sd[threadIdx.x] = drow[qbase + threadIdx.x];
    __syncthreads();

    const int p = blockIdx.x * 256 + threadIdx.x;
    const float tp = trow[p];
    const float dp = drow[p];
    float acc = 0.0f;
    for (int q = 0; q < 256; q += 4) {
        float4 tv = ((const float4*)st)[q >> 2];
        float4 dv = ((const float4*)sd)[q >> 2];
        acc += fabsf((tp - tv.x) * (dp - dv.x));
        acc += fabsf((tp - tv.y) * (dp - dv.y));
        acc += fabsf((tp - tv.z) * (dp - dv.z));
        acc += fabsf((tp - tv.w) * (dp - dv.w));
    }

    for (int off = 32; off > 0; off >>= 1) acc += __shfl_down(acc, off, 64);
    __shared__ float warp_acc[4];
    if ((threadIdx.x & 63) == 0) warp_acc[threadIdx.x >> 6] = acc;
    __syncthreads();
    if (threadIdx.x == 0) {
        const int bid = (blockIdx.z * gridDim.y + blockIdx.y) * gridDim.x + blockIdx.x;
        partials[bid] = warp_acc[0] + warp_acc[1] + warp_acc[2] + warp_acc[3];
    }
}

// Finalize: one block sums the 2048 partials, scales by 1/(2B), writes out.
// Overwrites the 0xAA poison directly -> no memset dispatch needed.
__global__ __launch_bounds__(256) void finalize_kernel(const float* __restrict__ partials,
                                                       float* __restrict__ out) {
    float acc = 0.0f;
    for (int i = threadIdx.x; i < NPAIRBLK; i += 256) acc += partials[i];
    for (int off = 32; off > 0; off >>= 1) acc += __shfl_down(acc, off, 64);
    __shared__ float warp_acc[4];
    if ((threadIdx.x & 63) == 0) warp_acc[threadIdx.x >> 6] = acc;
    __syncthreads();
    if (threadIdx.x == 0) {
        out[0] = (warp_acc[0] + warp_acc[1] + warp_acc[2] + warp_acc[3]) * (1.0f / (2.0f * BB));
    }
}

extern "C" void kernel_launch(void* const* d_in, const int* in_sizes, int n_in,
                              void* d_out, int out_size, void* d_ws, size_t ws_size,
                              hipStream_t stream) {
    const float* preds = (const float*)d_in[0];
    const float* targets = (const float*)d_in[1];
    float* out = (float*)d_out;
    float* disc = (float*)d_ws;                    // B*N floats = 256 KB
    float* partials = (float*)d_ws + BB * BN;      // 2048 floats

    dim3 gridA(BN / 32, BB);            // (64, 32) = 2048 blocks
    rank_disc_kernel<<<gridA, 256, 0, stream>>>(preds, disc);

    dim3 gridB(BN / 256, BB, BN / 256); // (8, 32, 8) = 2048 blocks
    pair_sum_kernel<<<gridB, 256, 0, stream>>>(targets, disc, partials);

    finalize_kernel<<<1, 256, 0, stream>>>(partials, out);
}